// Round 7
// baseline (275.243 us; speedup 1.0000x reference)
//
#include <hip/hip_runtime.h>

// Modular readout: 8 modules, each h = relu(x_m @ W1_m^T + b1_m); y_m = h @ W2_m^T + b2_m
// x [8192,4096] fp32; W1 [4096,4096] fp32 block-diag (8x 512x512); W2 [80,4096] fp32 block-diag
// out [8192,80] fp32 row-major (module-major columns).
//
// R12: R11 core-dumped from a launch-grid OOB in cvt_w_kernel: new granule count is
//      8*16*4*8*64 = 262144 but the grid stayed 2048*256 = 524288 -> threads j>=262144
//      wrote up to 8 MB into the 4 MB workspace (and read W1 OOB) -> device fault.
//      Fix: grid 1024 + hard bounds guard. Fused kernel unchanged from R11 (audited clean).
// R11 theory under test: R5/R8/R9/R10 (4 schedules) all ~86us, every pipe <=20%, identical
//      speed L3-resident -> per-iter cost is VMEM REQUEST-RATE (strided x loads touch 32
//      lines/instr, 4x re-request). Fix = contiguity, not scheduling:
//  - Block = 64 batch rows x FULL module (512 cols), grid 1024 (bid = tile*8 + m).
//    x slab staged ONCE to 64KB LDS bf16 via fully-contiguous 1KB/instr reads (8 req/instr);
//    granule-XOR g^((row&1)<<2) gives even bank spread for MFMA A-frag reads.
//  - W1 pre-pass writes MFMA-fragment-linear wb2[m][kk][wc][nt][lane][8bf16]: K-loop loads
//    B straight to REGISTERS with lane-contiguous 1KB instrs. No B-LDS, no DMA, NO K-loop
//    barriers (wave-private; compiler-scheduled 2-deep prefetch).
//  - Full-module blocks own their outputs: atomicAdd + init_out ELIMINATED; layer-2 reads
//    h from ldsH aliased over the consumed x-tile (same XOR convention).
//  - acc[4][8]=128 VGPRs + 2-deep B regs; __launch_bounds__(256,2): 2 blocks/CU (64KB LDS).

#define NMOD 8
#define DIM 512
#define OSZ 10
#define BATCH 8192
#define D_IN 4096
#define D_OUT 80
#define BM 64             // batch rows per block
#define NK 16             // K iters (512 / 32)
#define NGRAN (NMOD * 16 * 4 * 8 * 64)   // 262144 wb2 granules

// legacy tier-C sizes
#define LDSA_SZ 5120
#define LDSB_SZ 8192
#define HSTRIDE 264

typedef __attribute__((ext_vector_type(8))) short short8;   // 8 bf16 MFMA A/B frag
typedef __attribute__((ext_vector_type(4))) float float4v;  // MFMA C/D frag
typedef __attribute__((ext_vector_type(4))) unsigned int uint4v;
typedef __attribute__((ext_vector_type(2))) unsigned int uint2v;

__device__ __forceinline__ unsigned short f2bf(float f) {
    unsigned int u = __builtin_bit_cast(unsigned int, f);
    u += 0x7fffu + ((u >> 16) & 1u);   // RNE
    return (unsigned short)(u >> 16);
}

__device__ __forceinline__ unsigned int pk2(float a, float b) {
    unsigned int r;
    asm("v_cvt_pk_bf16_f32 %0, %1, %2" : "=v"(r) : "v"(a), "v"(b));
    return r;
}

// packed f32x8 -> bf16x8 via HW cvt_pk (RNE, same numerics as f2bf)
__device__ __forceinline__ short8 cvt8(float4 a, float4 b) {
    uint4v u = {pk2(a.x, a.y), pk2(a.z, a.w), pk2(b.x, b.y), pk2(b.z, b.w)};
    return __builtin_bit_cast(short8, u);
}

// ------- init (tier C only): out = broadcast b2 -------
__global__ void init_out_kernel(const float* __restrict__ b2, float* __restrict__ out) {
    int idx = blockIdx.x * 256 + threadIdx.x;            // 2560*256 = 655360 = 8192*80
    out[idx] = b2[idx % D_OUT];
}

// ------- tier B pre-pass: W1 diag blocks -> wb2 in MFMA-fragment-linear layout (4 MB) ----
// wb2 granule j = (((m*16 + kk)*4 + wc)*8 + nt)*64 + lane  holds
//   W1[m*512 + wc*128 + nt*16 + r16][m*512 + kk*32 + kq*8 .. +8] as bf16x8 (lane = kq*16+r16).
// 262144 granules -> grid 1024 x 256 (R12 fix; was 2048 -> 2x OOB -> device fault).
__global__ void cvt_w_kernel(const float* __restrict__ W1, ushort* __restrict__ wb2) {
    int j = blockIdx.x * 256 + threadIdx.x;
    if (j >= NGRAN) return;                              // hard guard
    int r16 = j & 15, kq = (j >> 4) & 3;
    int nt = (j >> 6) & 7, wc = (j >> 9) & 3, kk = (j >> 11) & 15, mm = j >> 15;
    int col = wc * 128 + nt * 16 + r16;
    int k   = kk * 32 + kq * 8;
    const float* p = W1 + (size_t)(mm * DIM + col) * D_IN + mm * DIM + k;
    *(short8*)(wb2 + (size_t)j * 8) = cvt8(*(const float4*)p, *(const float4*)(p + 4));
}

// ---------------- R12 barrier-free fused kernel (tier B) ----------------
// grid 1024: bid = tile*8 + m. block 256 (4 waves); wave wc owns hidden cols [wc*128,+128)
// for ALL 64 batch rows: acc[4][8] (mt = 16-row tile, nt = 16-col tile).
// LDS: xS [64 rows][512 shorts] = 65536 B (bf16 x-tile; aliased as ldsH in epilogue).
__global__ __launch_bounds__(256, 2)
void fused_full(const float* __restrict__ x, const ushort* __restrict__ wb2,
                const float* __restrict__ b1, const float* __restrict__ W2,
                const float* __restrict__ b2, float* __restrict__ out) {
    __shared__ __attribute__((aligned(16))) ushort xS[32768];   // 65536 B

    const int tid  = threadIdx.x;
    const int wc   = tid >> 6;                            // wave id = col group
    const int lane = tid & 63;
    const int r16  = lane & 15;
    const int kq   = lane >> 4;

    const int bid     = blockIdx.x;
    const int m       = bid & 7;                          // module -> XCD round-robin
    const int rowBase = (bid >> 3) * BM;

    // ---- stage x-tile: wave wc stages rows [wc*16, +16); fully contiguous 1KB reads ----
    {
        const float* xbase = x + (size_t)(rowBase + wc * 16) * D_IN + m * DIM;
#pragma unroll
        for (int i = 0; i < 32; i++) {
            const int r = i >> 1, h = i & 1;              // row r, 256-float half h
            const int row = wc * 16 + r;
            const float* p = xbase + (size_t)r * D_IN + h * 256 + lane * 4;
            float4 v = *(const float4*)p;                 // 64 lanes x 16B = 1KB contiguous
            const int g = h * 32 + (lane >> 1);           // granule 0..63 (8 bf16 each)
            const int addr = row * 512 + ((g ^ ((row & 1) << 2)) << 3) + ((lane & 1) << 2);
            uint2v w = {pk2(v.x, v.y), pk2(v.z, v.w)};
            *(uint2v*)(xS + addr) = w;                    // 8B write, 8B aligned
        }
    }
    __syncthreads();                                      // xS ready for all waves

    float b1v[8];
#pragma unroll
    for (int nt = 0; nt < 8; nt++)
        b1v[nt] = b1[m * DIM + wc * 128 + nt * 16 + r16];

    float4v acc[4][8];
#pragma unroll
    for (int i = 0; i < 4; i++)
#pragma unroll
        for (int j = 0; j < 8; j++) acc[i][j] = (float4v){0.f, 0.f, 0.f, 0.f};

    // ---- K-loop: barrier-free, wave-private; B reg-loaded lane-contiguous, 2-deep ----
    const ushort* wbase = wb2 + (size_t)m * 16 * 16384 + wc * 4096 + lane * 8;
    short8 bA[8], bB[8];

    auto loadB = [&](int kk, short8 (&bf)[8]) {
        const ushort* p = wbase + (size_t)kk * 16384;
#pragma unroll
        for (int nt = 0; nt < 8; nt++)                    // 8 x 1KB contiguous instrs
            bf[nt] = *(const short8*)(p + nt * 512);
    };
    auto step = [&](int kk, short8 (&bf)[8]) {
        short8 aF[4];
#pragma unroll
        for (int mt = 0; mt < 4; mt++) {
            const int row  = mt * 16 + r16;
            const int slot = (kk * 4 + kq) ^ ((r16 & 1) << 2);
            aF[mt] = *(const short8*)(xS + row * 512 + slot * 8);
        }
#pragma unroll
        for (int mt = 0; mt < 4; mt++)
#pragma unroll
            for (int nt = 0; nt < 8; nt++)
                acc[mt][nt] = __builtin_amdgcn_mfma_f32_16x16x32_bf16(aF[mt], bf[nt], acc[mt][nt], 0, 0, 0);
    };

    loadB(0, bA);
    for (int kk2 = 0; kk2 < NK; kk2 += 2) {
        loadB(kk2 + 1, bB);                               // prefetch odd
        step(kk2, bA);
        if (kk2 + 2 < NK) loadB(kk2 + 2, bA);             // prefetch next even
        step(kk2 + 1, bB);
    }

    // ---- epilogue: h -> ldsH (aliases xS, now fully consumed); fused layer 2 ----
    __syncthreads();                                      // all waves done reading xS
    ushort* ldsH = xS;
#pragma unroll
    for (int mt = 0; mt < 4; mt++) {
#pragma unroll
        for (int nt = 0; nt < 8; nt++) {
#pragma unroll
            for (int reg = 0; reg < 4; reg++) {
                float v = acc[mt][nt][reg] + b1v[nt];
                v = v > 0.f ? v : 0.f;
                const int row = mt * 16 + kq * 4 + reg;   // batch row 0..63 (row&1 == reg&1)
                const int col = wc * 128 + nt * 16 + r16; // hidden col 0..511
                const int g = col >> 3, c7 = col & 7;
                ldsH[row * 512 + ((g ^ ((reg & 1) << 2)) << 3) + c7] = f2bf(v);
            }
        }
    }
    __syncthreads();

    // layer 2: wave wc computes y rows [wc*16,+16): y = h[16][512] @ W2_m^T + b2
    {
        float4v acc2 = (float4v){0.f, 0.f, 0.f, 0.f};
        const float* w2row = W2 + (size_t)(m * OSZ + r16) * D_IN + m * DIM;
#pragma unroll
        for (int kc = 0; kc < 16; kc++) {
            const int row  = wc * 16 + r16;
            const int slot = (kc * 4 + kq) ^ ((r16 & 1) << 2);
            short8 hA = *(const short8*)(ldsH + row * 512 + slot * 8);
            short8 wb = {0, 0, 0, 0, 0, 0, 0, 0};
            if (r16 < OSZ) {
                const float* p = w2row + kc * 32 + kq * 8;
                wb = cvt8(*(const float4*)p, *(const float4*)(p + 4));
            }
            acc2 = __builtin_amdgcn_mfma_f32_16x16x32_bf16(hA, wb, acc2, 0, 0, 0);
        }
        if (r16 < OSZ) {
            const float bias = b2[m * OSZ + r16];
#pragma unroll
            for (int reg = 0; reg < 4; reg++) {
                const int grow = rowBase + wc * 16 + kq * 4 + reg;
                out[(size_t)grow * D_OUT + m * OSZ + r16] = acc2[reg] + bias;
            }
        }
    }
}

// ---------------- legacy fused kernel (tier C fallback, R5 structure) ----------------
__global__ __launch_bounds__(256, 2)
void fused_kernel(const float* __restrict__ x, const float* __restrict__ W1,
                  const float* __restrict__ b1, const float* __restrict__ W2,
                  float* __restrict__ out) {
    __shared__ __attribute__((aligned(16))) ushort smem[26624];   // 53248 B
    ushort* ldsA0 = smem;
    ushort* ldsA1 = smem + LDSA_SZ;
    ushort* ldsB0 = smem + 2 * LDSA_SZ;
    ushort* ldsB1 = smem + 2 * LDSA_SZ + LDSB_SZ;
    ushort* ldsH  = smem;

    const int tid  = threadIdx.x;
    const int wave = tid >> 6;
    const int lane = tid & 63;
    const int r16  = lane & 15;
    const int kq   = lane >> 4;

    const int bid     = blockIdx.x;
    const int m       = bid & 7;
    const int half    = (bid >> 3) & 1;
    const int rowBase = (bid >> 4) * 128;

    const float*  xsrc = x + (size_t)rowBase * D_IN + m * DIM;
    const float*  w1f  = W1 + (size_t)(m * DIM + half * 256) * D_IN + m * DIM;

    const int arow = tid >> 1;
    const int ah   = tid & 1;
    const int brow = tid >> 2;
    const int bc   = tid & 3;

    float4v acc[8][4];
#pragma unroll
    for (int i = 0; i < 8; i++)
#pragma unroll
        for (int j = 0; j < 4; j++) acc[i][j] = (float4v){0.f, 0.f, 0.f, 0.f};

#pragma unroll
    for (int r = 0; r < 4; r++) {
        const int row = r * 64 + brow;
        const int f   = (row >> 1) & 3;
        const float* p = w1f + (size_t)row * D_IN + bc * 8;
        *(short8*)(ldsB0 + row * 32 + (bc ^ f) * 8) = cvt8(*(const float4*)p, *(const float4*)(p + 4));
    }
    {
        const float* p = xsrc + (size_t)arow * D_IN + ah * 16;
        float4 a0 = *(const float4*)p, a1 = *(const float4*)(p + 4);
        float4 a2 = *(const float4*)(p + 8), a3 = *(const float4*)(p + 12);
        *(short8*)(ldsA0 + arow * 40 + ah * 16)     = cvt8(a0, a1);
        *(short8*)(ldsA0 + arow * 40 + ah * 16 + 8) = cvt8(a2, a3);
    }

    for (int kk = 0; kk < 16; kk++) {
        __syncthreads();
        ushort* Ac = (kk & 1) ? ldsA1 : ldsA0;
        ushort* Bc = (kk & 1) ? ldsB1 : ldsB0;
        ushort* An = (kk & 1) ? ldsA0 : ldsA1;
        ushort* Bn = (kk & 1) ? ldsB0 : ldsB1;

        float4 xr0, xr1, xr2, xr3;
        const bool pf = (kk < 15);
        if (pf) {
            const float* p = xsrc + (size_t)arow * D_IN + kk * 32 + 32 + ah * 16;
            xr0 = *(const float4*)p;     xr1 = *(const float4*)(p + 4);
            xr2 = *(const float4*)(p + 8); xr3 = *(const float4*)(p + 12);
        }

        short8 aF[8], bF[4];
#pragma unroll
        for (int mt = 0; mt < 8; mt++)
            aF[mt] = *(const short8*)(Ac + (mt * 16 + r16) * 40 + kq * 8);
#pragma unroll
        for (int nt = 0; nt < 4; nt++) {
            const int row = wave * 64 + nt * 16 + r16;
            bF[nt] = *(const short8*)(Bc + row * 32 + (kq ^ ((row >> 1) & 3)) * 8);
        }
#pragma unroll
        for (int mt = 0; mt < 8; mt++)
#pragma unroll
            for (int nt = 0; nt < 4; nt++)
                acc[mt][nt] = __builtin_amdgcn_mfma_f32_16x16x32_bf16(aF[mt], bF[nt], acc[mt][nt], 0, 0, 0);

        if (pf) {
            *(short8*)(An + arow * 40 + ah * 16)     = cvt8(xr0, xr1);
            *(short8*)(An + arow * 40 + ah * 16 + 8) = cvt8(xr2, xr3);
#pragma unroll
            for (int r = 0; r < 4; r++) {
                const int row = r * 64 + brow;
                const int f   = (row >> 1) & 3;
                const float* p = w1f + (size_t)row * D_IN + kk * 32 + 32 + bc * 8;
                *(short8*)(Bn + row * 32 + (bc ^ f) * 8) = cvt8(*(const float4*)p, *(const float4*)(p + 4));
            }
        }
    }

    float b1v[4];
#pragma unroll
    for (int nt = 0; nt < 4; nt++)
        b1v[nt] = b1[m * DIM + half * 256 + wave * 64 + nt * 16 + r16];

    for (int hh = 0; hh < 2; hh++) {
        __syncthreads();
#pragma unroll
        for (int mt2 = 0; mt2 < 4; mt2++) {
            const int mt = hh * 4 + mt2;
#pragma unroll
            for (int nt = 0; nt < 4; nt++) {
#pragma unroll
                for (int reg = 0; reg < 4; reg++) {
                    float v = acc[mt][nt][reg] + b1v[nt];
                    v = v > 0.f ? v : 0.f;
                    const int lr  = mt2 * 16 + kq * 4 + reg;
                    const int col = wave * 64 + nt * 16 + r16;
                    ldsH[lr * HSTRIDE + col] = f2bf(v);
                }
            }
        }
        __syncthreads();

        {
            float4v acc2 = (float4v){0.f, 0.f, 0.f, 0.f};
            const int hrow = wave * 16 + r16;
            const float* w2row = W2 + (size_t)(m * OSZ + r16) * D_IN + m * DIM + half * 256;
#pragma unroll
            for (int kc = 0; kc < 8; kc++) {
                const int c = kc * 32 + kq * 8;
                short8 hA = *(const short8*)(ldsH + hrow * HSTRIDE + c);
                short8 wb = {0, 0, 0, 0, 0, 0, 0, 0};
                if (r16 < OSZ) {
                    const float* p = w2row + c;
                    wb = cvt8(*(const float4*)p, *(const float4*)(p + 4));
                }
                acc2 = __builtin_amdgcn_mfma_f32_16x16x32_bf16(hA, wb, acc2, 0, 0, 0);
            }
            if (r16 < OSZ) {
#pragma unroll
                for (int reg = 0; reg < 4; reg++) {
                    const int grow = rowBase + hh * 64 + wave * 16 + kq * 4 + reg;
                    atomicAdd(out + (size_t)grow * D_OUT + m * OSZ + r16, acc2[reg]);
                }
            }
        }
    }
}

extern "C" void kernel_launch(void* const* d_in, const int* in_sizes, int n_in,
                              void* d_out, int out_size, void* d_ws, size_t ws_size,
                              hipStream_t stream) {
    const float* x  = (const float*)d_in[0];
    const float* W1 = (const float*)d_in[1];
    const float* b1 = (const float*)d_in[2];
    const float* W2 = (const float*)d_in[3];
    const float* b2 = (const float*)d_in[4];
    float* out = (float*)d_out;

    if (ws_size >= (size_t)NMOD * DIM * DIM * sizeof(ushort)) {   // 4 MB: tier B
        ushort* wb2 = (ushort*)d_ws;
        cvt_w_kernel<<<dim3(1024), dim3(256), 0, stream>>>(W1, wb2);   // 262144 granules
        fused_full<<<dim3(1024), dim3(256), 0, stream>>>(x, wb2, b1, W2, b2, out);
    } else {                                                      // tier C: zero workspace
        init_out_kernel<<<dim3(2560), dim3(256), 0, stream>>>(b2, out);
        fused_kernel<<<dim3(1024), dim3(256), 0, stream>>>(x, W1, b1, W2, out);
    }
}